// Round 6
// baseline (558.322 us; speedup 1.0000x reference)
//
#include <hip/hip_runtime.h>

#define BB 1024
#define TT 512
#define HH 64
#define NB 2            // batches per block -> grid 512 -> 2 blocks/CU
#define NTHR 512        // 8 waves, same per-wave structure as round-3 best

typedef _Float16 half8 __attribute__((ext_vector_type(8)));
typedef float f32x4 __attribute__((ext_vector_type(4)));

#if defined(__has_builtin)
#  if __has_builtin(__builtin_amdgcn_rcpf)
#    define FRCP(v) __builtin_amdgcn_rcpf(v)
#  endif
#endif
#ifndef FRCP
#  define FRCP(v) (1.0f / (v))
#endif

#define MFMA16(A, B, C) __builtin_amdgcn_mfma_f32_16x16x32_f16((A), (B), (C), 0, 0, 0)

__device__ __forceinline__ float fsig(float v) {
    return FRCP(1.0f + __expf(-v));
}
__device__ __forceinline__ float ftanh(float v) {
    return fmaf(2.0f, fsig(2.0f * v), -1.0f);
}

// A-fragment loader: element e = W[row][k0+e]; same (lane-group,e)->k bijection
// as the B fragment, so the contraction is exact under any HW k permutation.
__device__ __forceinline__ half8 load_frag(const float* __restrict__ W, int row, int k0) {
    const float4* p = (const float4*)(W + row * HH + k0);
    float4 u = p[0], v = p[1];
    half8 r;
    r[0] = (_Float16)u.x; r[1] = (_Float16)u.y; r[2] = (_Float16)u.z; r[3] = (_Float16)u.w;
    r[4] = (_Float16)v.x; r[5] = (_Float16)v.y; r[6] = (_Float16)v.z; r[7] = (_Float16)v.w;
    return r;
}

// Register-resident MFMA LSTM — round-3 wave structure, 2 barrier groups/CU.
// Identical per-wave profile to the 288us round-3 kernel (2 tiles/wave,
// 12 MFMA/wave, biases as MFMA C-in, VGPR~76) but NB=2 so grid=512 gives two
// independent blocks per CU: one block's ds/MFMA/transcendental latency chain
// and barrier drain overlap the other block's issue.
// Wave w owns units 8w..8w+7 via 2 row-permuted tiles dd=0..1:
// within-tile row i <- W row (i&3)*64 + 8w + 4dd + (i>>2); lane (g4,col) reg q
// holds gate q of unit 8w+4dd+g4, batch col&1 (cols replicate 8x). Replica
// index (col>>1): layer=bit0, dtile=bits1-2 (only dtile<2 active in phase 2;
// other lanes are exec-masked there).
__global__ __launch_bounds__(NTHR, 2)
void lstm_mfma5(const float* __restrict__ x,     // [B,T] (I=1)
                const float* __restrict__ Wih0,  // [256]
                const float* __restrict__ Whh0,  // [256,64]
                const float* __restrict__ bih0,  // [256]
                const float* __restrict__ bhh0,  // [256]
                const float* __restrict__ Wih1,  // [256,64]
                const float* __restrict__ Whh1,  // [256,64]
                const float* __restrict__ bih1,  // [256]
                const float* __restrict__ bhh1,  // [256]
                const float* __restrict__ Wfc,   // [64]
                const float* __restrict__ bfc,   // [1]
                float* __restrict__ out)         // [B]
{
    __shared__ float s_x[NB][TT + 1];
    __shared__ __align__(16) _Float16 s_h0b[2][NB][80];   // double-buffered
    __shared__ __align__(16) _Float16 s_h1b[2][NB][80];

    const int t    = threadIdx.x;
    const int lane = t & 63;
    const int w    = t >> 6;          // wave 0..7
    const int b0   = blockIdx.x * NB;

    const int arow = lane & 15;       // A/B row within tile; D col
    const int g4   = lane >> 4;       // k-group 0..3
    const int bsrc = lane & 1;        // batch (B cols replicate 8x)
    const int rep    = (lane >> 1) & 7;
    const int layer  = rep & 1;
    const int dtile  = rep >> 1;      // 0..3; only 0..1 are real tiles
    const int ddv    = dtile & 1;     // clamped tile index (safe for loads)
    const int active0 = (dtile < 2);  // lane owns a phase-2 task
    const int u      = 8 * w + 4 * ddv + g4;   // my unit (always in [0,64))

    // ---- one-time: A fragments (permuted rows): 12 half8 = 48 VGPR ----
    half8 a0[2][2], a1i[2][2], a1h[2][2];   // [tile][k-half]
#pragma unroll
    for (int d = 0; d < 2; ++d) {
        const int row = (arow & 3) * 64 + 8 * w + 4 * d + (arow >> 2);
#pragma unroll
        for (int kk = 0; kk < 2; ++kk) {
            const int k0 = kk * 32 + g4 * 8;
            a0[d][kk]  = load_frag(Whh0, row, k0);
            a1i[d][kk] = load_frag(Wih1, row, k0);
            a1h[d][kk] = load_frag(Whh1, row, k0);
        }
    }

    // ---- biases as MFMA C-in (16 regs) ----
    f32x4 cb0[2], cb1[2];
#pragma unroll
    for (int d = 0; d < 2; ++d) {
        const int uu = 8 * w + 4 * d + g4;
#pragma unroll
        for (int q = 0; q < 4; ++q) {
            const int r = q * 64 + uu;
            cb0[d][q] = bih0[r] + bhh0[r];
            cb1[d][q] = bih1[r] + bhh1[r];
        }
    }
    // x weight for my task's 4 gates (layer-1 lanes: 0)
    float xw[4];
#pragma unroll
    for (int q = 0; q < 4; ++q) {
        xw[q] = (layer == 0) ? Wih0[q * 64 + u] : 0.0f;
    }

    // ---- stage x (coalesced) ----
#pragma unroll
    for (int k = 0; k < (NB * TT) / NTHR; ++k) {
        int idx = t + NTHR * k;
        int nb  = idx >> 9;          // / TT
        int pos = idx & (TT - 1);
        s_x[nb][pos] = x[(b0 + nb) * TT + pos];
    }
    // zero both h buffers
    {
        _Float16* z0 = &s_h0b[0][0][0];
        _Float16* z1 = &s_h1b[0][0][0];
        for (int i = t; i < 2 * NB * 80; i += NTHR) {
            z0[i] = (_Float16)0.0f;
            z1[i] = (_Float16)0.0f;
        }
    }

    float cst = 0.0f;   // my task's cell state
    __syncthreads();

    for (int s = 0; s <= TT; ++s) {
        const int rb = s & 1;        // read buffer
        const int wb = rb ^ 1;       // write buffer
        const int xs = (s < TT) ? s : (TT - 1);
        const float xv = s_x[bsrc][xs];

        const _Float16* h0p = &s_h0b[rb][bsrc][g4 * 8];
        const _Float16* h1p = &s_h1b[rb][bsrc][g4 * 8];
        half8 bh0_0 = *(const half8*)(h0p);        // k 0..31
        half8 bh0_1 = *(const half8*)(h0p + 32);   // k 32..63
        half8 bh1_0 = *(const half8*)(h1p);
        half8 bh1_1 = *(const half8*)(h1p + 32);

        // layer-0 gates (Whh0.h0 + bias0), 2-deep chains
        f32x4 c0_0 = cb0[0], c0_1 = cb0[1];
        c0_0 = MFMA16(a0[0][0], bh0_0, c0_0);
        c0_1 = MFMA16(a0[1][0], bh0_0, c0_1);
        c0_0 = MFMA16(a0[0][1], bh0_1, c0_0);
        c0_1 = MFMA16(a0[1][1], bh0_1, c0_1);
        // layer-1 gates (Wih1.h0 + Whh1.h1 + bias1), split accumulators
        f32x4 c1a0 = cb1[0], c1a1 = cb1[1];
        f32x4 c1b0 = {0.f, 0.f, 0.f, 0.f}, c1b1 = {0.f, 0.f, 0.f, 0.f};
        c1a0 = MFMA16(a1i[0][0], bh0_0, c1a0);
        c1a1 = MFMA16(a1i[1][0], bh0_0, c1a1);
        c1b0 = MFMA16(a1h[0][0], bh1_0, c1b0);
        c1b1 = MFMA16(a1h[1][0], bh1_0, c1b1);
        c1a0 = MFMA16(a1i[0][1], bh0_1, c1a0);
        c1a1 = MFMA16(a1i[1][1], bh0_1, c1a1);
        c1b0 = MFMA16(a1h[0][1], bh1_1, c1b0);
        c1b1 = MFMA16(a1h[1][1], bh1_1, c1b1);
        f32x4 c1_0 = c1a0 + c1b0;
        f32x4 c1_1 = c1a1 + c1b1;

        // lane-local task select (no shuffles, no LDS)
        f32x4 t0 = ddv ? c0_1 : c0_0;
        f32x4 t1 = ddv ? c1_1 : c1_0;
        f32x4 gv = layer ? t1 : t0;

        float gi = fmaf(xw[0], xv, gv[0]);
        float gf = fmaf(xw[1], xv, gv[1]);
        float gg = fmaf(xw[2], xv, gv[2]);
        float go = fmaf(xw[3], xv, gv[3]);

        const bool act = active0 && (layer ? (s >= 1) : (s < TT));
        if (act) {
            float i_ = fsig(gi);
            float f_ = fsig(gf);
            float g_ = ftanh(gg);
            float o_ = fsig(go);
            cst = fmaf(f_, cst, i_ * g_);
            float hn = o_ * ftanh(cst);
            _Float16* dst = layer ? &s_h1b[wb][bsrc][u] : &s_h0b[wb][bsrc][u];
            *dst = (_Float16)hn;
        }
        __syncthreads();
    }

    // ---- epilogue: out[b] = h1_last . Wfc + bfc ----
    // last write (s=TT, TT even) went to buffer 1
    if (t < NB * HH) {
        const int nb = t >> 6;
        const int j  = t & 63;
        float v = (float)s_h1b[1][nb][j] * Wfc[j];
#pragma unroll
        for (int off = 32; off > 0; off >>= 1) {
            v += __shfl_down(v, off);
        }
        if (j == 0) out[b0 + nb] = v + bfc[0];
    }
}

extern "C" void kernel_launch(void* const* d_in, const int* in_sizes, int n_in,
                              void* d_out, int out_size, void* d_ws, size_t ws_size,
                              hipStream_t stream) {
    const float* x    = (const float*)d_in[0];
    const float* Wih0 = (const float*)d_in[1];
    const float* Whh0 = (const float*)d_in[2];
    const float* bih0 = (const float*)d_in[3];
    const float* bhh0 = (const float*)d_in[4];
    const float* Wih1 = (const float*)d_in[5];
    const float* Whh1 = (const float*)d_in[6];
    const float* bih1 = (const float*)d_in[7];
    const float* bhh1 = (const float*)d_in[8];
    const float* Wfc  = (const float*)d_in[9];
    const float* bfc  = (const float*)d_in[10];
    float* out = (float*)d_out;

    lstm_mfma5<<<dim3(BB / NB), dim3(NTHR), 0, stream>>>(
        x, Wih0, Whh0, bih0, bhh0, Wih1, Whh1, bih1, bhh1, Wfc, bfc, out);
}

// Round 7
// 374.369 us; speedup vs baseline: 1.4914x; 1.4914x over previous
//
#include <hip/hip_runtime.h>

#define BB 1024
#define TT 512
#define HH 64
#define NB 4            // batches per block
#define NTHR 1024       // 16 waves -> 4 waves/SIMD in ONE block per CU

typedef _Float16 half8 __attribute__((ext_vector_type(8)));
typedef float f32x4 __attribute__((ext_vector_type(4)));

#if defined(__has_builtin)
#  if __has_builtin(__builtin_amdgcn_rcpf)
#    define FRCP(v) __builtin_amdgcn_rcpf(v)
#  endif
#endif
#ifndef FRCP
#  define FRCP(v) (1.0f / (v))
#endif

#define MFMA16(A, B, C) __builtin_amdgcn_mfma_f32_16x16x32_f16((A), (B), (C), 0, 0, 0)

__device__ __forceinline__ float fsig(float v) {
    return FRCP(1.0f + __expf(-v));
}
__device__ __forceinline__ float ftanh(float v) {
    return fmaf(2.0f, fsig(2.0f * v), -1.0f);
}

// A-fragment loader: element e = W[row][k0+e]; same (lane-group,e)->k bijection
// as the B fragment, so the contraction is exact under any HW k permutation.
__device__ __forceinline__ half8 load_frag(const float* __restrict__ W, int row, int k0) {
    const float4* p = (const float4*)(W + row * HH + k0);
    float4 u = p[0], v = p[1];
    half8 r;
    r[0] = (_Float16)u.x; r[1] = (_Float16)u.y; r[2] = (_Float16)u.z; r[3] = (_Float16)u.w;
    r[4] = (_Float16)v.x; r[5] = (_Float16)v.y; r[6] = (_Float16)v.z; r[7] = (_Float16)v.w;
    return r;
}

// Register-resident MFMA LSTM — 16-wave single-block-per-CU edition.
// R6 post-mortem: multi-block TLP never gets resident (unified reg file caps
// 8-wave blocks at 1/CU). Instead: ONE 1024-thread block per CU, 1 tile/wave
// -> per-wave demand ~90 regs -> 4 waves/SIMD resident, hiding the serial
// ds_read->MFMA->activation chain that dominated the 2-waves/SIMD wall.
// Wave w owns units 4w..4w+3 via one row-permuted tile:
// within-tile row i <- W row (i&3)*64 + 4w + (i>>2). After MFMA, lane
// (g4=lane>>4, col=lane&15) reg q = gate q of unit 4w+g4, batch col&3
// (cols replicate 4x). Replica (col>>2): layer=bit0, active iff bit1==0.
// 32 tasks/wave x 16 waves = 512 = 2 layers x 4 batches x 64 units, exact.
__global__ __launch_bounds__(NTHR, 4)
void lstm_mfma6(const float* __restrict__ x,     // [B,T] (I=1)
                const float* __restrict__ Wih0,  // [256]
                const float* __restrict__ Whh0,  // [256,64]
                const float* __restrict__ bih0,  // [256]
                const float* __restrict__ bhh0,  // [256]
                const float* __restrict__ Wih1,  // [256,64]
                const float* __restrict__ Whh1,  // [256,64]
                const float* __restrict__ bih1,  // [256]
                const float* __restrict__ bhh1,  // [256]
                const float* __restrict__ Wfc,   // [64]
                const float* __restrict__ bfc,   // [1]
                float* __restrict__ out)         // [B]
{
    __shared__ float s_x[NB][TT + 1];
    __shared__ __align__(16) _Float16 s_h0b[2][NB][80];   // double-buffered
    __shared__ __align__(16) _Float16 s_h1b[2][NB][80];

    const int t    = threadIdx.x;
    const int lane = t & 63;
    const int w    = t >> 6;          // wave 0..15
    const int b0   = blockIdx.x * NB;

    const int arow = lane & 15;       // A/B row within tile; D col
    const int g4   = lane >> 4;       // k-group 0..3
    const int bsrc = lane & 3;        // batch (B cols replicate 4x)
    const int rep    = (lane >> 2) & 3;
    const int layer  = rep & 1;
    const int actrep = ((rep >> 1) == 0);   // lane owns a phase-2 task
    const int u      = 4 * w + g4;          // my unit (0..63)

    // ---- one-time: A fragments (permuted rows): 6 half8 = 24 VGPR ----
    half8 a0[2], a1i[2], a1h[2];      // [k-half]
    {
        const int row = (arow & 3) * 64 + 4 * w + (arow >> 2);
#pragma unroll
        for (int kk = 0; kk < 2; ++kk) {
            const int k0 = kk * 32 + g4 * 8;
            a0[kk]  = load_frag(Whh0, row, k0);
            a1i[kk] = load_frag(Wih1, row, k0);
            a1h[kk] = load_frag(Whh1, row, k0);
        }
    }

    // ---- biases as MFMA C-in (8 regs): valid for every lane's (g4,q) ----
    f32x4 cb0, cb1;
#pragma unroll
    for (int q = 0; q < 4; ++q) {
        const int r = q * 64 + u;
        cb0[q] = bih0[r] + bhh0[r];
        cb1[q] = bih1[r] + bhh1[r];
    }
    // x weight for my task's 4 gates (layer-1 lanes: 0)
    float xw[4];
#pragma unroll
    for (int q = 0; q < 4; ++q) {
        xw[q] = (layer == 0) ? Wih0[q * 64 + u] : 0.0f;
    }

    // ---- stage x (coalesced) ----
#pragma unroll
    for (int k = 0; k < (NB * TT) / NTHR; ++k) {
        int idx = t + NTHR * k;
        int nb  = idx >> 9;          // / TT
        int pos = idx & (TT - 1);
        s_x[nb][pos] = x[(b0 + nb) * TT + pos];
    }
    // zero both h buffers (2*NB*80 = 640 elems per array)
    if (t < 2 * NB * 80) {
        (&s_h0b[0][0][0])[t] = (_Float16)0.0f;
        (&s_h1b[0][0][0])[t] = (_Float16)0.0f;
    }

    float cst = 0.0f;   // my task's cell state
    __syncthreads();

    for (int s = 0; s <= TT; ++s) {
        const int rb = s & 1;        // read buffer
        const int wb = rb ^ 1;       // write buffer
        const int xs = (s < TT) ? s : (TT - 1);
        const float xv = s_x[bsrc][xs];

        const _Float16* h0p = &s_h0b[rb][bsrc][g4 * 8];
        const _Float16* h1p = &s_h1b[rb][bsrc][g4 * 8];
        half8 bh0_0 = *(const half8*)(h0p);        // k 0..31
        half8 bh0_1 = *(const half8*)(h0p + 32);   // k 32..63
        half8 bh1_0 = *(const half8*)(h1p);
        half8 bh1_1 = *(const half8*)(h1p + 32);

        // layer-0 gates: 2-deep chain; layer-1: two 2-deep chains + add
        f32x4 c0 = cb0;
        c0 = MFMA16(a0[0], bh0_0, c0);
        c0 = MFMA16(a0[1], bh0_1, c0);
        f32x4 c1a = cb1;
        f32x4 c1b = {0.f, 0.f, 0.f, 0.f};
        c1a = MFMA16(a1i[0], bh0_0, c1a);
        c1b = MFMA16(a1h[0], bh1_0, c1b);
        c1a = MFMA16(a1i[1], bh0_1, c1a);
        c1b = MFMA16(a1h[1], bh1_1, c1b);
        f32x4 c1 = c1a + c1b;

        // lane-local task select (single cndmask set)
        f32x4 gv = layer ? c1 : c0;

        float gi = fmaf(xw[0], xv, gv[0]);
        float gf = fmaf(xw[1], xv, gv[1]);
        float gg = fmaf(xw[2], xv, gv[2]);
        float go = fmaf(xw[3], xv, gv[3]);

        const bool act = actrep && (layer ? (s >= 1) : (s < TT));
        if (act) {
            float i_ = fsig(gi);
            float f_ = fsig(gf);
            float g_ = ftanh(gg);
            float o_ = fsig(go);
            cst = fmaf(f_, cst, i_ * g_);
            float hn = o_ * ftanh(cst);
            _Float16* dst = layer ? &s_h1b[wb][bsrc][u] : &s_h0b[wb][bsrc][u];
            *dst = (_Float16)hn;
        }
        __syncthreads();
    }

    // ---- epilogue: out[b] = h1_last . Wfc + bfc ----
    // last write (s=TT, TT even) went to buffer 1
    if (t < NB * HH) {
        const int nb = t >> 6;
        const int j  = t & 63;
        float v = (float)s_h1b[1][nb][j] * Wfc[j];
#pragma unroll
        for (int off = 32; off > 0; off >>= 1) {
            v += __shfl_down(v, off);
        }
        if (j == 0) out[b0 + nb] = v + bfc[0];
    }
}

extern "C" void kernel_launch(void* const* d_in, const int* in_sizes, int n_in,
                              void* d_out, int out_size, void* d_ws, size_t ws_size,
                              hipStream_t stream) {
    const float* x    = (const float*)d_in[0];
    const float* Wih0 = (const float*)d_in[1];
    const float* Whh0 = (const float*)d_in[2];
    const float* bih0 = (const float*)d_in[3];
    const float* bhh0 = (const float*)d_in[4];
    const float* Wih1 = (const float*)d_in[5];
    const float* Whh1 = (const float*)d_in[6];
    const float* bih1 = (const float*)d_in[7];
    const float* bhh1 = (const float*)d_in[8];
    const float* Wfc  = (const float*)d_in[9];
    const float* bfc  = (const float*)d_in[10];
    float* out = (float*)d_out;

    lstm_mfma6<<<dim3(BB / NB), dim3(NTHR), 0, stream>>>(
        x, Wih0, Whh0, bih0, bhh0, Wih1, Whh1, bih1, bhh1, Wfc, bfc, out);
}

// Round 8
// 294.168 us; speedup vs baseline: 1.8980x; 1.2726x over previous
//
#include <hip/hip_runtime.h>

#define BB 1024
#define TT 512
#define HH 64
#define NB 4            // batches per block
#define NTHR 512        // 8 waves — the R3 sweet spot

typedef _Float16 half8 __attribute__((ext_vector_type(8)));
typedef float f32x4 __attribute__((ext_vector_type(4)));

#if defined(__has_builtin)
#  if __has_builtin(__builtin_amdgcn_rcpf)
#    define FRCP(v) __builtin_amdgcn_rcpf(v)
#  endif
#endif
#ifndef FRCP
#  define FRCP(v) (1.0f / (v))
#endif

#define MFMA16(A, B, C) __builtin_amdgcn_mfma_f32_16x16x32_f16((A), (B), (C), 0, 0, 0)

__device__ __forceinline__ float fsig(float v) {
    return FRCP(1.0f + __expf(-v));
}
__device__ __forceinline__ float ftanh(float v) {
    return fmaf(2.0f, fsig(2.0f * v), -1.0f);
}

// A-fragment loader: element e = W[row][k0+e]; same (lane-group,e)->k bijection
// as the B fragment, so the contraction is exact under any HW k permutation.
__device__ __forceinline__ half8 load_frag(const float* __restrict__ W, int row, int k0) {
    const float4* p = (const float4*)(W + row * HH + k0);
    float4 u = p[0], v = p[1];
    half8 r;
    r[0] = (_Float16)u.x; r[1] = (_Float16)u.y; r[2] = (_Float16)u.z; r[3] = (_Float16)u.w;
    r[4] = (_Float16)v.x; r[5] = (_Float16)v.y; r[6] = (_Float16)v.z; r[7] = (_Float16)v.w;
    return r;
}

// Register-resident MFMA LSTM — R3 structure (288us), loop-overhead-stripped.
// R4-R7 showed the 8-wave/NB=4 shape is the unique register-clean point with
// all lanes tasked; this round removes per-iteration scaffolding instead:
// 2x-unrolled steady state with compile-time buffer parity (LDS bases hoisted)
// and NO predicates/clamps (both layers always active for 1<=s<=511);
// layer-0-only s=0 and layer-1-only s=512 are peeled.
__global__ __launch_bounds__(NTHR, 2)
void lstm_mfma7(const float* __restrict__ x,     // [B,T] (I=1)
                const float* __restrict__ Wih0,  // [256]
                const float* __restrict__ Whh0,  // [256,64]
                const float* __restrict__ bih0,  // [256]
                const float* __restrict__ bhh0,  // [256]
                const float* __restrict__ Wih1,  // [256,64]
                const float* __restrict__ Whh1,  // [256,64]
                const float* __restrict__ bih1,  // [256]
                const float* __restrict__ bhh1,  // [256]
                const float* __restrict__ Wfc,   // [64]
                const float* __restrict__ bfc,   // [1]
                float* __restrict__ out)         // [B]
{
    __shared__ float s_x[NB][TT + 1];
    __shared__ __align__(16) _Float16 s_h0b[2][NB][80];   // double-buffered
    __shared__ __align__(16) _Float16 s_h1b[2][NB][80];

    const int t    = threadIdx.x;
    const int lane = t & 63;
    const int w    = t >> 6;          // wave 0..7
    const int b0   = blockIdx.x * NB;

    const int arow = lane & 15;       // A/B row within tile; D col
    const int g4   = lane >> 4;       // k-group 0..3
    const int bsrc = lane & 3;        // batch (B cols replicate 4x)
    const int rep   = (lane >> 2) & 3;
    const int layer = rep & 1;
    const int dd    = rep >> 1;       // which tile's gates this lane finishes
    const int u     = 8 * w + 4 * dd + g4;   // my unit

    // ---- one-time: A fragments (permuted rows): 12 half8 = 48 VGPR ----
    half8 a0[2][2], a1i[2][2], a1h[2][2];   // [tile][k-half]
#pragma unroll
    for (int d = 0; d < 2; ++d) {
        const int row = (arow & 3) * 64 + 8 * w + 4 * d + (arow >> 2);
#pragma unroll
        for (int kk = 0; kk < 2; ++kk) {
            const int k0 = kk * 32 + g4 * 8;
            a0[d][kk]  = load_frag(Whh0, row, k0);
            a1i[d][kk] = load_frag(Wih1, row, k0);
            a1h[d][kk] = load_frag(Whh1, row, k0);
        }
    }

    // ---- biases as MFMA C-in (16 regs) ----
    f32x4 cb0[2], cb1[2];
#pragma unroll
    for (int d = 0; d < 2; ++d) {
        const int uu = 8 * w + 4 * d + g4;
#pragma unroll
        for (int q = 0; q < 4; ++q) {
            const int r = q * 64 + uu;
            cb0[d][q] = bih0[r] + bhh0[r];
            cb1[d][q] = bih1[r] + bhh1[r];
        }
    }
    // x weight for my task's 4 gates (layer-1 lanes: 0)
    float xw[4];
#pragma unroll
    for (int q = 0; q < 4; ++q) {
        xw[q] = (layer == 0) ? Wih0[q * 64 + u] : 0.0f;
    }

    // ---- stage x (coalesced) ----
#pragma unroll
    for (int k = 0; k < (NB * TT) / NTHR; ++k) {
        int idx = t + NTHR * k;
        int nb  = idx >> 9;          // / TT
        int pos = idx & (TT - 1);
        s_x[nb][pos] = x[(b0 + nb) * TT + pos];
    }
    // zero both h buffers
    {
        _Float16* z0 = &s_h0b[0][0][0];
        _Float16* z1 = &s_h1b[0][0][0];
        for (int i = t; i < 2 * NB * 80; i += NTHR) {
            z0[i] = (_Float16)0.0f;
            z1[i] = (_Float16)0.0f;
        }
    }

    float cst = 0.0f;                       // my task's cell state
    const float* xp = &s_x[bsrc][0];        // hoisted per-lane x base
    __syncthreads();

    // One full pipeline step. RB: compile-time read-buffer parity.
    // L0/L1: compile-time layer-activity (only differ at s=0 / s=512).
#define STEP(RB, L0, L1, XS)                                                  \
    {                                                                         \
        const float xv = xp[XS];                                              \
        const _Float16* h0p = &s_h0b[RB][bsrc][g4 * 8];                       \
        const _Float16* h1p = &s_h1b[RB][bsrc][g4 * 8];                       \
        half8 bh0_0 = *(const half8*)(h0p);                                   \
        half8 bh0_1 = *(const half8*)(h0p + 32);                              \
        half8 bh1_0 = *(const half8*)(h1p);                                   \
        half8 bh1_1 = *(const half8*)(h1p + 32);                              \
        f32x4 c0_0 = cb0[0], c0_1 = cb0[1];                                   \
        c0_0 = MFMA16(a0[0][0], bh0_0, c0_0);                                 \
        c0_1 = MFMA16(a0[1][0], bh0_0, c0_1);                                 \
        c0_0 = MFMA16(a0[0][1], bh0_1, c0_0);                                 \
        c0_1 = MFMA16(a0[1][1], bh0_1, c0_1);                                 \
        f32x4 c1a0 = cb1[0], c1a1 = cb1[1];                                   \
        f32x4 c1b0 = {0.f, 0.f, 0.f, 0.f}, c1b1 = {0.f, 0.f, 0.f, 0.f};       \
        c1a0 = MFMA16(a1i[0][0], bh0_0, c1a0);                                \
        c1a1 = MFMA16(a1i[1][0], bh0_0, c1a1);                                \
        c1b0 = MFMA16(a1h[0][0], bh1_0, c1b0);                                \
        c1b1 = MFMA16(a1h[1][0], bh1_0, c1b1);                                \
        c1a0 = MFMA16(a1i[0][1], bh0_1, c1a0);                                \
        c1a1 = MFMA16(a1i[1][1], bh0_1, c1a1);                                \
        c1b0 = MFMA16(a1h[0][1], bh1_1, c1b0);                                \
        c1b1 = MFMA16(a1h[1][1], bh1_1, c1b1);                                \
        f32x4 c1_0 = c1a0 + c1b0;                                             \
        f32x4 c1_1 = c1a1 + c1b1;                                             \
        f32x4 t0 = dd ? c0_1 : c0_0;                                          \
        f32x4 t1 = dd ? c1_1 : c1_0;                                          \
        f32x4 gv = layer ? t1 : t0;                                           \
        float gi = fmaf(xw[0], xv, gv[0]);                                    \
        float gf = fmaf(xw[1], xv, gv[1]);                                    \
        float gg = fmaf(xw[2], xv, gv[2]);                                    \
        float go = fmaf(xw[3], xv, gv[3]);                                    \
        if ((L0) && (L1)) {                                                   \
            float i_ = fsig(gi);                                              \
            float f_ = fsig(gf);                                              \
            float g_ = ftanh(gg);                                             \
            float o_ = fsig(go);                                              \
            cst = fmaf(f_, cst, i_ * g_);                                     \
            float hn = o_ * ftanh(cst);                                       \
            _Float16* dst = layer ? &s_h1b[RB ^ 1][bsrc][u]                   \
                                  : &s_h0b[RB ^ 1][bsrc][u];                  \
            *dst = (_Float16)hn;                                              \
        } else if (L0) {                                                      \
            if (layer == 0) {                                                 \
                float i_ = fsig(gi);                                          \
                float f_ = fsig(gf);                                          \
                float g_ = ftanh(gg);                                         \
                float o_ = fsig(go);                                          \
                cst = fmaf(f_, cst, i_ * g_);                                 \
                s_h0b[RB ^ 1][bsrc][u] = (_Float16)(o_ * ftanh(cst));         \
            }                                                                 \
        } else {                                                              \
            if (layer == 1) {                                                 \
                float i_ = fsig(gi);                                          \
                float f_ = fsig(gf);                                          \
                float g_ = ftanh(gg);                                         \
                float o_ = fsig(go);                                          \
                cst = fmaf(f_, cst, i_ * g_);                                 \
                s_h1b[RB ^ 1][bsrc][u] = (_Float16)(o_ * ftanh(cst));         \
            }                                                                 \
        }                                                                     \
        __syncthreads();                                                      \
    }

    // s = 0: layer 0 only (h buffers are zero; layer-1 must not touch cst)
    STEP(0, 1, 0, 0)
    // steady state: s = 1..510, both layers active, compile-time parity
    {
        int s = 1;
#pragma nounroll
        for (int it = 0; it < (TT - 2) / 2; ++it) {   // 255 iters -> s=1..510
            STEP(1, 1, 1, s)
            STEP(0, 1, 1, s + 1)
            s += 2;
        }
    }
    // s = 511 (odd parity)
    STEP(1, 1, 1, 511)
    // s = 512: layer 1 only (computes timestep 511; x index unused -> 511)
    STEP(0, 0, 1, 511)
#undef STEP

    // ---- epilogue: out[b] = h1_last . Wfc + bfc ----
    // last write (s=512, RB=0) went to buffer 1
    if (t < NB * HH) {
        const int nb = t >> 6;
        const int j  = t & 63;
        float v = (float)s_h1b[1][nb][j] * Wfc[j];
#pragma unroll
        for (int off = 32; off > 0; off >>= 1) {
            v += __shfl_down(v, off);
        }
        if (j == 0) out[b0 + nb] = v + bfc[0];
    }
}

extern "C" void kernel_launch(void* const* d_in, const int* in_sizes, int n_in,
                              void* d_out, int out_size, void* d_ws, size_t ws_size,
                              hipStream_t stream) {
    const float* x    = (const float*)d_in[0];
    const float* Wih0 = (const float*)d_in[1];
    const float* Whh0 = (const float*)d_in[2];
    const float* bih0 = (const float*)d_in[3];
    const float* bhh0 = (const float*)d_in[4];
    const float* Wih1 = (const float*)d_in[5];
    const float* Whh1 = (const float*)d_in[6];
    const float* bih1 = (const float*)d_in[7];
    const float* bhh1 = (const float*)d_in[8];
    const float* Wfc  = (const float*)d_in[9];
    const float* bfc  = (const float*)d_in[10];
    float* out = (float*)d_out;

    lstm_mfma7<<<dim3(BB / NB), dim3(NTHR), 0, stream>>>(
        x, Wih0, Whh0, bih0, bhh0, Wih1, Whh1, bih1, bhh1, Wfc, bfc, out);
}

// Round 9
// 293.202 us; speedup vs baseline: 1.9042x; 1.0033x over previous
//
#include <hip/hip_runtime.h>

#define BB 1024
#define TT 512
#define HH 64
#define NB 4            // batches per block
#define NTHR 512        // 8 waves — the R3/R8 sweet spot

typedef _Float16 half8 __attribute__((ext_vector_type(8)));
typedef float f32x4 __attribute__((ext_vector_type(4)));

#if defined(__has_builtin)
#  if __has_builtin(__builtin_amdgcn_rcpf)
#    define FRCP(v) __builtin_amdgcn_rcpf(v)
#  endif
#endif
#ifndef FRCP
#  define FRCP(v) (1.0f / (v))
#endif

#define MFMA16(A, B, C) __builtin_amdgcn_mfma_f32_16x16x32_f16((A), (B), (C), 0, 0, 0)

__device__ __forceinline__ float fsig(float v) {
    return FRCP(1.0f + __expf(-v));
}
__device__ __forceinline__ float ftanh(float v) {
    return fmaf(2.0f, fsig(2.0f * v), -1.0f);
}

// A-fragment loader: element e = W[row][k0+e]; same (lane-group,e)->k bijection
// as the B fragment, so the contraction is exact under any HW k permutation.
__device__ __forceinline__ half8 load_frag(const float* __restrict__ W, int row, int k0) {
    const float4* p = (const float4*)(W + row * HH + k0);
    float4 u = p[0], v = p[1];
    half8 r;
    r[0] = (_Float16)u.x; r[1] = (_Float16)u.y; r[2] = (_Float16)u.z; r[3] = (_Float16)u.w;
    r[4] = (_Float16)v.x; r[5] = (_Float16)v.y; r[6] = (_Float16)v.z; r[7] = (_Float16)v.w;
    return r;
}

// Register-resident MFMA LSTM — R8 structure with two pipe-pressure cuts:
// (1) layer-1 gates as ONE K=128 concatenated chain [Wih1|Whh1].[h0;h1]
//     per tile (4-deep MFMA chain) — removes the c1a+c1b merge (8 v_add) and
//     frees 8 accumulator VGPRs;
// (2) x read from GLOBAL (L1-resident, vmem pipe) instead of LDS — removes
//     8 ds_read_b32/CU-ts from the contended LDS pipe + the staging prologue.
// Everything else identical to the 269us R8 kernel: 2x-unrolled steady state
// with compile-time buffer parity, peeled s=0 / s=512, biases as MFMA C-in,
// lane-local task finish via (layer,dd) replica bits.
__global__ __launch_bounds__(NTHR, 2)
void lstm_mfma8(const float* __restrict__ x,     // [B,T] (I=1)
                const float* __restrict__ Wih0,  // [256]
                const float* __restrict__ Whh0,  // [256,64]
                const float* __restrict__ bih0,  // [256]
                const float* __restrict__ bhh0,  // [256]
                const float* __restrict__ Wih1,  // [256,64]
                const float* __restrict__ Whh1,  // [256,64]
                const float* __restrict__ bih1,  // [256]
                const float* __restrict__ bhh1,  // [256]
                const float* __restrict__ Wfc,   // [64]
                const float* __restrict__ bfc,   // [1]
                float* __restrict__ out)         // [B]
{
    __shared__ __align__(16) _Float16 s_h0b[2][NB][80];   // double-buffered
    __shared__ __align__(16) _Float16 s_h1b[2][NB][80];

    const int t    = threadIdx.x;
    const int lane = t & 63;
    const int w    = t >> 6;          // wave 0..7
    const int b0   = blockIdx.x * NB;

    const int arow = lane & 15;       // A/B row within tile; D col
    const int g4   = lane >> 4;       // k-group 0..3
    const int bsrc = lane & 3;        // batch (B cols replicate 4x)
    const int rep   = (lane >> 2) & 3;
    const int layer = rep & 1;
    const int dd    = rep >> 1;       // which tile's gates this lane finishes
    const int u     = 8 * w + 4 * dd + g4;   // my unit

    // ---- one-time: A fragments (permuted rows): 12 half8 = 48 VGPR ----
    half8 a0[2][2], a1i[2][2], a1h[2][2];   // [tile][k-half]
#pragma unroll
    for (int d = 0; d < 2; ++d) {
        const int row = (arow & 3) * 64 + 8 * w + 4 * d + (arow >> 2);
#pragma unroll
        for (int kk = 0; kk < 2; ++kk) {
            const int k0 = kk * 32 + g4 * 8;
            a0[d][kk]  = load_frag(Whh0, row, k0);
            a1i[d][kk] = load_frag(Wih1, row, k0);
            a1h[d][kk] = load_frag(Whh1, row, k0);
        }
    }

    // ---- biases as MFMA C-in (16 regs) ----
    f32x4 cb0[2], cb1[2];
#pragma unroll
    for (int d = 0; d < 2; ++d) {
        const int uu = 8 * w + 4 * d + g4;
#pragma unroll
        for (int q = 0; q < 4; ++q) {
            const int r = q * 64 + uu;
            cb0[d][q] = bih0[r] + bhh0[r];
            cb1[d][q] = bih1[r] + bhh1[r];
        }
    }
    // x weight for my task's 4 gates (layer-1 lanes: 0)
    float xw[4];
#pragma unroll
    for (int q = 0; q < 4; ++q) {
        xw[q] = (layer == 0) ? Wih0[q * 64 + u] : 0.0f;
    }

    // per-lane global x pointer (4 distinct addrs/wave; L1-resident, 2KB/row)
    const float* __restrict__ xgp = x + (size_t)(b0 + bsrc) * TT;

    // zero both h buffers
    {
        _Float16* z0 = &s_h0b[0][0][0];
        _Float16* z1 = &s_h1b[0][0][0];
        for (int i = t; i < 2 * NB * 80; i += NTHR) {
            z0[i] = (_Float16)0.0f;
            z1[i] = (_Float16)0.0f;
        }
    }

    float cst = 0.0f;                       // my task's cell state
    __syncthreads();

    // One full pipeline step. RB: compile-time read-buffer parity.
    // L0/L1: compile-time layer-activity (only differ at s=0 / s=512).
#define STEP(RB, L0, L1, XS)                                                  \
    {                                                                         \
        const float xv = xgp[XS];                                             \
        const _Float16* h0p = &s_h0b[RB][bsrc][g4 * 8];                       \
        const _Float16* h1p = &s_h1b[RB][bsrc][g4 * 8];                       \
        half8 bh0_0 = *(const half8*)(h0p);                                   \
        half8 bh0_1 = *(const half8*)(h0p + 32);                              \
        half8 bh1_0 = *(const half8*)(h1p);                                   \
        half8 bh1_1 = *(const half8*)(h1p + 32);                              \
        f32x4 c0_0 = cb0[0], c0_1 = cb0[1];                                   \
        c0_0 = MFMA16(a0[0][0], bh0_0, c0_0);                                 \
        c0_1 = MFMA16(a0[1][0], bh0_0, c0_1);                                 \
        c0_0 = MFMA16(a0[0][1], bh0_1, c0_0);                                 \
        c0_1 = MFMA16(a0[1][1], bh0_1, c0_1);                                 \
        /* layer-1: K=128 concat chain per tile, no accumulator merge */      \
        f32x4 c1_0 = cb1[0], c1_1 = cb1[1];                                   \
        c1_0 = MFMA16(a1i[0][0], bh0_0, c1_0);                                \
        c1_1 = MFMA16(a1i[1][0], bh0_0, c1_1);                                \
        c1_0 = MFMA16(a1i[0][1], bh0_1, c1_0);                                \
        c1_1 = MFMA16(a1i[1][1], bh0_1, c1_1);                                \
        c1_0 = MFMA16(a1h[0][0], bh1_0, c1_0);                                \
        c1_1 = MFMA16(a1h[1][0], bh1_0, c1_1);                                \
        c1_0 = MFMA16(a1h[0][1], bh1_1, c1_0);                                \
        c1_1 = MFMA16(a1h[1][1], bh1_1, c1_1);                                \
        f32x4 t0 = dd ? c0_1 : c0_0;                                          \
        f32x4 t1 = dd ? c1_1 : c1_0;                                          \
        f32x4 gv = layer ? t1 : t0;                                           \
        float gi = fmaf(xw[0], xv, gv[0]);                                    \
        float gf = fmaf(xw[1], xv, gv[1]);                                    \
        float gg = fmaf(xw[2], xv, gv[2]);                                    \
        float go = fmaf(xw[3], xv, gv[3]);                                    \
        if ((L0) && (L1)) {                                                   \
            float i_ = fsig(gi);                                              \
            float f_ = fsig(gf);                                              \
            float g_ = ftanh(gg);                                             \
            float o_ = fsig(go);                                              \
            cst = fmaf(f_, cst, i_ * g_);                                     \
            float hn = o_ * ftanh(cst);                                       \
            _Float16* dst = layer ? &s_h1b[RB ^ 1][bsrc][u]                   \
                                  : &s_h0b[RB ^ 1][bsrc][u];                  \
            *dst = (_Float16)hn;                                              \
        } else if (L0) {                                                      \
            if (layer == 0) {                                                 \
                float i_ = fsig(gi);                                          \
                float f_ = fsig(gf);                                          \
                float g_ = ftanh(gg);                                         \
                float o_ = fsig(go);                                          \
                cst = fmaf(f_, cst, i_ * g_);                                 \
                s_h0b[RB ^ 1][bsrc][u] = (_Float16)(o_ * ftanh(cst));         \
            }                                                                 \
        } else {                                                              \
            if (layer == 1) {                                                 \
                float i_ = fsig(gi);                                          \
                float f_ = fsig(gf);                                          \
                float g_ = ftanh(gg);                                         \
                float o_ = fsig(go);                                          \
                cst = fmaf(f_, cst, i_ * g_);                                 \
                s_h1b[RB ^ 1][bsrc][u] = (_Float16)(o_ * ftanh(cst));         \
            }                                                                 \
        }                                                                     \
        __syncthreads();                                                      \
    }

    // s = 0: layer 0 only (h buffers are zero; layer-1 must not touch cst)
    STEP(0, 1, 0, 0)
    // steady state: s = 1..510, both layers active, compile-time parity
    {
        int s = 1;
#pragma nounroll
        for (int it = 0; it < (TT - 2) / 2; ++it) {   // 255 iters -> s=1..510
            STEP(1, 1, 1, s)
            STEP(0, 1, 1, s + 1)
            s += 2;
        }
    }
    // s = 511 (odd parity)
    STEP(1, 1, 1, 511)
    // s = 512: layer 1 only (computes timestep 511; x index unused -> 511)
    STEP(0, 0, 1, 511)
#undef STEP

    // ---- epilogue: out[b] = h1_last . Wfc + bfc ----
    // last write (s=512, RB=0) went to buffer 1
    if (t < NB * HH) {
        const int nb = t >> 6;
        const int j  = t & 63;
        float v = (float)s_h1b[1][nb][j] * Wfc[j];
#pragma unroll
        for (int off = 32; off > 0; off >>= 1) {
            v += __shfl_down(v, off);
        }
        if (j == 0) out[b0 + nb] = v + bfc[0];
    }
}

extern "C" void kernel_launch(void* const* d_in, const int* in_sizes, int n_in,
                              void* d_out, int out_size, void* d_ws, size_t ws_size,
                              hipStream_t stream) {
    const float* x    = (const float*)d_in[0];
    const float* Wih0 = (const float*)d_in[1];
    const float* Whh0 = (const float*)d_in[2];
    const float* bih0 = (const float*)d_in[3];
    const float* bhh0 = (const float*)d_in[4];
    const float* Wih1 = (const float*)d_in[5];
    const float* Whh1 = (const float*)d_in[6];
    const float* bih1 = (const float*)d_in[7];
    const float* bhh1 = (const float*)d_in[8];
    const float* Wfc  = (const float*)d_in[9];
    const float* bfc  = (const float*)d_in[10];
    float* out = (float*)d_out;

    lstm_mfma8<<<dim3(BB / NB), dim3(NTHR), 0, stream>>>(
        x, Wih0, Whh0, bih0, bhh0, Wih1, Whh1, bih1, bhh1, Wfc, bfc, out);
}

// Round 10
// 290.959 us; speedup vs baseline: 1.9189x; 1.0077x over previous
//
#include <hip/hip_runtime.h>

#define BB 1024
#define TT 512
#define HH 64
#define NB 4            // batches per block
#define NTHR 512        // 8 waves — the R3/R8/R9 sweet spot

typedef _Float16 half8 __attribute__((ext_vector_type(8)));
typedef float f32x4 __attribute__((ext_vector_type(4)));

#if defined(__has_builtin)
#  if __has_builtin(__builtin_amdgcn_rcpf)
#    define FRCP(v) __builtin_amdgcn_rcpf(v)
#  endif
#  if __has_builtin(__builtin_amdgcn_exp2f)
#    define FEXP2(v) __builtin_amdgcn_exp2f(v)
#  endif
#endif
#ifndef FRCP
#  define FRCP(v) (1.0f / (v))
#endif
#ifndef FEXP2
#  define FEXP2(v) exp2f(v)
#endif

#define MFMA16(A, B, C) __builtin_amdgcn_mfma_f32_16x16x32_f16((A), (B), (C), 0, 0, 0)

#define L2E 1.4426950408889634f

// Gates arrive PRE-SCALED into exp2 domain: gi/gf/go = -log2e*G, gg = -2log2e*G.
// sig(G) = rcp(1+exp2(-log2e*G)); tanh(G) = 2*rcp(1+exp2(-2log2e*G)) - 1.
__device__ __forceinline__ float lstm_act(float gi, float gf, float gg, float go,
                                          float& cst) {
    float i_ = FRCP(1.0f + FEXP2(gi));
    float f_ = FRCP(1.0f + FEXP2(gf));
    float o_ = FRCP(1.0f + FEXP2(go));
    float g_ = fmaf(2.0f, FRCP(1.0f + FEXP2(gg)), -1.0f);
    cst = fmaf(f_, cst, i_ * g_);
    float e2 = FEXP2(cst * (-2.0f * L2E));            // cst is true-domain
    return fmaf(2.0f * o_, FRCP(1.0f + e2), -o_);     // o*tanh(cst), one fma tail
}

// A-fragment loader with gate prescale folded into the f16 weights.
// Element e = W[row][k0+e]*sc; same (lane-group,e)->k bijection as the B
// fragment, so the contraction is exact under any HW k permutation.
__device__ __forceinline__ half8 load_frag(const float* __restrict__ W, int row,
                                           int k0, float sc) {
    const float4* p = (const float4*)(W + row * HH + k0);
    float4 u = p[0], v = p[1];
    half8 r;
    r[0] = (_Float16)(u.x * sc); r[1] = (_Float16)(u.y * sc);
    r[2] = (_Float16)(u.z * sc); r[3] = (_Float16)(u.w * sc);
    r[4] = (_Float16)(v.x * sc); r[5] = (_Float16)(v.y * sc);
    r[6] = (_Float16)(v.z * sc); r[7] = (_Float16)(v.w * sc);
    return r;
}

// Register-resident MFMA LSTM — R9 structure + critical-path micro-cuts:
// (1) exp2-domain prescale of weights/biases/xw (kills the per-activation
//     v_mul by log2e on the dependent path);
// (2) layer-1 gates back to two 2-deep MFMA chains + add (half the dependent
//     MFMA latency on the h1-producing lanes);
// (3) x values for both unrolled steps loaded at body top (VMEM latency
//     hidden for the second step);
// (4) o*tanh(cst) tail as a single fma.
__global__ __launch_bounds__(NTHR, 2)
void lstm_mfma9(const float* __restrict__ x,     // [B,T] (I=1)
                const float* __restrict__ Wih0,  // [256]
                const float* __restrict__ Whh0,  // [256,64]
                const float* __restrict__ bih0,  // [256]
                const float* __restrict__ bhh0,  // [256]
                const float* __restrict__ Wih1,  // [256,64]
                const float* __restrict__ Whh1,  // [256,64]
                const float* __restrict__ bih1,  // [256]
                const float* __restrict__ bhh1,  // [256]
                const float* __restrict__ Wfc,   // [64]
                const float* __restrict__ bfc,   // [1]
                float* __restrict__ out)         // [B]
{
    __shared__ __align__(16) _Float16 s_h0b[2][NB][80];   // double-buffered
    __shared__ __align__(16) _Float16 s_h1b[2][NB][80];

    const int t    = threadIdx.x;
    const int lane = t & 63;
    const int w    = t >> 6;          // wave 0..7
    const int b0   = blockIdx.x * NB;

    const int arow = lane & 15;       // A/B row within tile; D col
    const int g4   = lane >> 4;       // k-group 0..3
    const int bsrc = lane & 3;        // batch (B cols replicate 4x)
    const int rep   = (lane >> 2) & 3;
    const int layer = rep & 1;
    const int dd    = rep >> 1;       // which tile's gates this lane finishes
    const int u     = 8 * w + 4 * dd + g4;   // my unit

    // per-row gate index for the A fragment = arow&3 (row = (arow&3)*64 + ...)
    const int   gq  = arow & 3;
    const float fsc = (gq == 2) ? (-2.0f * L2E) : (-L2E);

    // ---- one-time: A fragments (permuted rows, prescaled): 12 half8 ----
    half8 a0[2][2], a1i[2][2], a1h[2][2];   // [tile][k-half]
#pragma unroll
    for (int d = 0; d < 2; ++d) {
        const int row = gq * 64 + 8 * w + 4 * d + (arow >> 2);
#pragma unroll
        for (int kk = 0; kk < 2; ++kk) {
            const int k0 = kk * 32 + g4 * 8;
            a0[d][kk]  = load_frag(Whh0, row, k0, fsc);
            a1i[d][kk] = load_frag(Wih1, row, k0, fsc);
            a1h[d][kk] = load_frag(Whh1, row, k0, fsc);
        }
    }

    // ---- biases as MFMA C-in (prescaled per gate q) ----
    f32x4 cb0[2], cb1[2];
#pragma unroll
    for (int d = 0; d < 2; ++d) {
        const int uu = 8 * w + 4 * d + g4;
#pragma unroll
        for (int q = 0; q < 4; ++q) {
            const int r = q * 64 + uu;
            const float sq = (q == 2) ? (-2.0f * L2E) : (-L2E);
            cb0[d][q] = (bih0[r] + bhh0[r]) * sq;
            cb1[d][q] = (bih1[r] + bhh1[r]) * sq;
        }
    }
    // x weight for my task's 4 gates, prescaled (layer-1 lanes: 0)
    float xw[4];
#pragma unroll
    for (int q = 0; q < 4; ++q) {
        const float sq = (q == 2) ? (-2.0f * L2E) : (-L2E);
        xw[q] = (layer == 0) ? (Wih0[q * 64 + u] * sq) : 0.0f;
    }

    // per-lane global x pointer (4 distinct addrs/wave; L1/L2-resident)
    const float* __restrict__ xgp = x + (size_t)(b0 + bsrc) * TT;

    // zero both h buffers
    {
        _Float16* z0 = &s_h0b[0][0][0];
        _Float16* z1 = &s_h1b[0][0][0];
        for (int i = t; i < 2 * NB * 80; i += NTHR) {
            z0[i] = (_Float16)0.0f;
            z1[i] = (_Float16)0.0f;
        }
    }

    float cst = 0.0f;                       // my task's cell state
    __syncthreads();

    // One full pipeline step. RB: compile-time read-buffer parity.
    // L0/L1: compile-time layer-activity. XV: preloaded x value.
#define STEP(RB, L0, L1, XV)                                                  \
    {                                                                         \
        const _Float16* h0p = &s_h0b[RB][bsrc][g4 * 8];                       \
        const _Float16* h1p = &s_h1b[RB][bsrc][g4 * 8];                       \
        half8 bh0_0 = *(const half8*)(h0p);                                   \
        half8 bh0_1 = *(const half8*)(h0p + 32);                              \
        half8 bh1_0 = *(const half8*)(h1p);                                   \
        half8 bh1_1 = *(const half8*)(h1p + 32);                              \
        f32x4 c0_0 = cb0[0], c0_1 = cb0[1];                                   \
        c0_0 = MFMA16(a0[0][0], bh0_0, c0_0);                                 \
        c0_1 = MFMA16(a0[1][0], bh0_0, c0_1);                                 \
        c0_0 = MFMA16(a0[0][1], bh0_1, c0_0);                                 \
        c0_1 = MFMA16(a0[1][1], bh0_1, c0_1);                                 \
        /* layer-1: two 2-deep chains per tile + add (short dep chain) */     \
        f32x4 c1a0 = cb1[0], c1a1 = cb1[1];                                   \
        f32x4 c1b0 = {0.f, 0.f, 0.f, 0.f}, c1b1 = {0.f, 0.f, 0.f, 0.f};       \
        c1a0 = MFMA16(a1i[0][0], bh0_0, c1a0);                                \
        c1a1 = MFMA16(a1i[1][0], bh0_0, c1a1);                                \
        c1b0 = MFMA16(a1h[0][0], bh1_0, c1b0);                                \
        c1b1 = MFMA16(a1h[1][0], bh1_0, c1b1);                                \
        c1a0 = MFMA16(a1i[0][1], bh0_1, c1a0);                                \
        c1a1 = MFMA16(a1i[1][1], bh0_1, c1a1);                                \
        c1b0 = MFMA16(a1h[0][1], bh1_1, c1b0);                                \
        c1b1 = MFMA16(a1h[1][1], bh1_1, c1b1);                                \
        f32x4 c1_0 = c1a0 + c1b0;                                             \
        f32x4 c1_1 = c1a1 + c1b1;                                             \
        f32x4 t0 = dd ? c0_1 : c0_0;                                          \
        f32x4 t1 = dd ? c1_1 : c1_0;                                          \
        f32x4 gv = layer ? t1 : t0;                                           \
        float gi = fmaf(xw[0], (XV), gv[0]);                                  \
        float gf = fmaf(xw[1], (XV), gv[1]);                                  \
        float gg = fmaf(xw[2], (XV), gv[2]);                                  \
        float go = fmaf(xw[3], (XV), gv[3]);                                  \
        if ((L0) && (L1)) {                                                   \
            float hn = lstm_act(gi, gf, gg, go, cst);                         \
            _Float16* dst = layer ? &s_h1b[RB ^ 1][bsrc][u]                   \
                                  : &s_h0b[RB ^ 1][bsrc][u];                  \
            *dst = (_Float16)hn;                                              \
        } else if (L0) {                                                      \
            if (layer == 0) {                                                 \
                float hn = lstm_act(gi, gf, gg, go, cst);                     \
                s_h0b[RB ^ 1][bsrc][u] = (_Float16)hn;                        \
            }                                                                 \
        } else {                                                              \
            if (layer == 1) {                                                 \
                float hn = lstm_act(gi, gf, gg, go, cst);                     \
                s_h1b[RB ^ 1][bsrc][u] = (_Float16)hn;                        \
            }                                                                 \
        }                                                                     \
        __syncthreads();                                                      \
    }

    // s = 0: layer 0 only (h buffers are zero; layer-1 must not touch cst)
    STEP(0, 1, 0, xgp[0])
    // steady state: s = 1..510, both layers active, compile-time parity;
    // both x values loaded at body top so the 2nd step's load is hidden.
    {
        int s = 1;
#pragma nounroll
        for (int it = 0; it < (TT - 2) / 2; ++it) {   // 255 iters -> s=1..510
            const float xA = xgp[s];
            const float xB = xgp[s + 1];
            STEP(1, 1, 1, xA)
            STEP(0, 1, 1, xB)
            s += 2;
        }
    }
    // s = 511 (odd parity)
    STEP(1, 1, 1, xgp[511])
    // s = 512: layer 1 only (x unused by layer-1 lanes: xw==0)
    STEP(0, 0, 1, 0.0f)
#undef STEP

    // ---- epilogue: out[b] = h1_last . Wfc + bfc ----
    // last write (s=512, RB=0) went to buffer 1
    if (t < NB * HH) {
        const int nb = t >> 6;
        const int j  = t & 63;
        float v = (float)s_h1b[1][nb][j] * Wfc[j];
#pragma unroll
        for (int off = 32; off > 0; off >>= 1) {
            v += __shfl_down(v, off);
        }
        if (j == 0) out[b0 + nb] = v + bfc[0];
    }
}

extern "C" void kernel_launch(void* const* d_in, const int* in_sizes, int n_in,
                              void* d_out, int out_size, void* d_ws, size_t ws_size,
                              hipStream_t stream) {
    const float* x    = (const float*)d_in[0];
    const float* Wih0 = (const float*)d_in[1];
    const float* Whh0 = (const float*)d_in[2];
    const float* bih0 = (const float*)d_in[3];
    const float* bhh0 = (const float*)d_in[4];
    const float* Wih1 = (const float*)d_in[5];
    const float* Whh1 = (const float*)d_in[6];
    const float* bih1 = (const float*)d_in[7];
    const float* bhh1 = (const float*)d_in[8];
    const float* Wfc  = (const float*)d_in[9];
    const float* bfc  = (const float*)d_in[10];
    float* out = (float*)d_out;

    lstm_mfma9<<<dim3(BB / NB), dim3(NTHR), 0, stream>>>(
        x, Wih0, Whh0, bih0, bhh0, Wih1, Whh1, bih1, bhh1, Wfc, bfc, out);
}